// Round 5
// baseline (4332.538 us; speedup 1.0000x reference)
//
#include <hip/hip_runtime.h>
#include <cstdint>

#define D_MODEL 2048
#define T_SEQ   2048
#define NQH     32
#define NKVH    8
#define HD      64
#define DIM_KV  512

typedef __attribute__((ext_vector_type(4))) float f32x4;

#define NEG_BIG (-1e30f)

// ---------------------------------------------------------------------------
// Dead-simple correct GEMM: C[m][n] = sum_k A[m][k] * W[k][n], all fp32.
// W in natural [K][N] layout. One thread per output element.
// A-load wave-uniform (broadcast); W-load coalesced across lanes.
// ---------------------------------------------------------------------------
__global__ __launch_bounds__(256) void gemm_simple(const float* __restrict__ A,
                                                   const float* __restrict__ W,
                                                   float* __restrict__ C,
                                                   int M, int N, int K) {
    int n = blockIdx.x * 256 + threadIdx.x;
    int m = blockIdx.y;
    if (n >= N || m >= M) return;
    float acc = 0.f;
#pragma unroll 8
    for (int k = 0; k < K; k++)
        acc += A[(size_t)m * K + k] * W[(size_t)k * N + n];
    C[(size_t)m * N + n] = acc;
}

// ---------------------------------------------------------------------------
// In-place RoPE on X[T][cols] (fp32), head dim 64 (32 pairs/head).
// pair i of head H at columns H*64+2i, H*64+2i+1; angle = t * theta^(-i/32)
// ---------------------------------------------------------------------------
__global__ void rope_kernel(float* __restrict__ X, int T, int cols) {
    int idx = blockIdx.x * blockDim.x + threadIdx.x;
    int ppr = cols >> 1;
    if (idx >= T * ppr) return;
    int t = idx / ppr;
    int j = idx - t * ppr;
    int i = j & 31;
    int col = ((j >> 5) << 6) + (i << 1);
    // inv_freq = theta^(-i/32); ln(500000) = 13.122363377404328
    float inv = expf(-(float)i * (13.122363377404328f / 32.0f));
    float ang = (float)t * inv;
    float c = cosf(ang), s = sinf(ang);
    size_t base = (size_t)t * cols + col;
    float x1 = X[base];
    float x2 = X[base + 1];
    X[base]     = x1 * c - x2 * s;
    X[base + 1] = x1 * s + x2 * c;
}

// ---------------------------------------------------------------------------
// Dead-simple correct causal GQA attention: one thread per (head, query row),
// serial online softmax over keys. Ob may alias Q: each thread reads exactly
// the Q cells it later writes, fully into registers, before any store.
// (No __restrict__ on Q/Ob because they alias.)
// ---------------------------------------------------------------------------
__global__ __launch_bounds__(256) void attn_simple(const float* Q,
                                                   const float* __restrict__ Kb,
                                                   const float* __restrict__ Vb,
                                                   float* Ob) {
    int qi = blockIdx.x * 256 + threadIdx.x;   // query row
    int h  = blockIdx.y;                        // q head
    int hk = h >> 2;                            // kv head (GQA 4:1)

    float qv[64], o[64];
    {
        const f32x4* Qr = (const f32x4*)(Q + (size_t)qi * D_MODEL + h * HD);
#pragma unroll
        for (int g = 0; g < 16; g++) {
            f32x4 qq = Qr[g];
            qv[g * 4 + 0] = qq.x; qv[g * 4 + 1] = qq.y;
            qv[g * 4 + 2] = qq.z; qv[g * 4 + 3] = qq.w;
        }
#pragma unroll
        for (int d = 0; d < 64; d++) o[d] = 0.f;
    }

    float m = NEG_BIG, l = 0.f;
    int jmax = blockIdx.x * 256 + 255;   // max query row in this block
    for (int j = 0; j <= jmax; j++) {
        const f32x4* Kr = (const f32x4*)(Kb + (size_t)j * DIM_KV + hk * HD);
        float s = 0.f;
#pragma unroll
        for (int g = 0; g < 16; g++) {
            f32x4 kk = Kr[g];
            s += qv[g * 4 + 0] * kk.x + qv[g * 4 + 1] * kk.y
               + qv[g * 4 + 2] * kk.z + qv[g * 4 + 3] * kk.w;
        }
        s *= 0.125f;                       // HEAD_DIM^-0.5
        if (j > qi) s = NEG_BIG;           // causal mask (finite, NaN-proof)
        float mn    = fmaxf(m, s);
        float alpha = __expf(m - mn);
        float p     = __expf(s - mn);
        l = l * alpha + p;
        const f32x4* Vr = (const f32x4*)(Vb + (size_t)j * DIM_KV + hk * HD);
#pragma unroll
        for (int g = 0; g < 16; g++) {
            f32x4 vv = Vr[g];
            o[g * 4 + 0] = o[g * 4 + 0] * alpha + p * vv.x;
            o[g * 4 + 1] = o[g * 4 + 1] * alpha + p * vv.y;
            o[g * 4 + 2] = o[g * 4 + 2] * alpha + p * vv.z;
            o[g * 4 + 3] = o[g * 4 + 3] * alpha + p * vv.w;
        }
        m = mn;
    }

    float inv = (l > 0.f) ? 1.0f / l : 0.f;
#pragma unroll
    for (int d = 0; d < 64; d++)
        Ob[(size_t)qi * D_MODEL + h * HD + d] = o[d] * inv;
}

// ---------------------------------------------------------------------------
extern "C" void kernel_launch(void* const* d_in, const int* in_sizes, int n_in,
                              void* d_out, int out_size, void* d_ws, size_t ws_size,
                              hipStream_t stream) {
    const float* q_embs = (const float*)d_in[0];
    const float* k_embs = (const float*)d_in[1];
    const float* v_embs = (const float*)d_in[2];
    const float* w_q = (const float*)d_in[3];
    const float* w_k = (const float*)d_in[4];
    const float* w_v = (const float*)d_in[5];
    const float* w_o = (const float*)d_in[6];
    float* out = (float*)d_out;

    const size_t M1 = (size_t)1024 * 1024;
    float* base = (float*)d_ws;
    // fp32 workspace, 24 MB total at the front of d_ws:
    //   Qb [0, 4M) floats  (16 MB) — also attention output (safe alias)
    //   Kb [4M, 5M) (4 MB), Vb [5M, 6M) (4 MB)
    float* Qb = base + 0 * M1;
    float* Kb = base + 4 * M1;
    float* Vb = base + 5 * M1;
    float* Ab = Qb;   // attention output aliases Qb (see attn_simple)

    dim3 blk(256);
    // projections: X[T,2048] @ W[2048,N]
    gemm_simple<<<dim3(8, 2048), blk, 0, stream>>>(q_embs, w_q, Qb, 2048, 2048, 2048);
    gemm_simple<<<dim3(2, 2048), blk, 0, stream>>>(k_embs, w_k, Kb, 2048, 512, 2048);
    gemm_simple<<<dim3(2, 2048), blk, 0, stream>>>(v_embs, w_v, Vb, 2048, 512, 2048);

    rope_kernel<<<(2048 * 1024 + 255) / 256, blk, 0, stream>>>(Qb, 2048, 2048);
    rope_kernel<<<(2048 * 256 + 255) / 256, blk, 0, stream>>>(Kb, 2048, 512);

    attn_simple<<<dim3(8, 32), blk, 0, stream>>>(Qb, Kb, Vb, Ab);

    // output projection: Ab[T,2048] @ w_o[2048,2048] -> out (fp32)
    gemm_simple<<<dim3(8, 2048), blk, 0, stream>>>(Ab, w_o, out, 2048, 2048, 2048);
}

// Round 6
// 1128.508 us; speedup vs baseline: 3.8392x; 3.8392x over previous
//
#include <hip/hip_runtime.h>
#include <hip/hip_bf16.h>
#include <cstdint>

#define D_MODEL 2048
#define T_SEQ   2048
#define NQH     32
#define NKVH    8
#define HD      64
#define DIM_KV  512

typedef __attribute__((ext_vector_type(8))) __bf16 bf16x8;
typedef __attribute__((ext_vector_type(4))) float  f32x4;
typedef __attribute__((ext_vector_type(4))) unsigned int u32x4;
typedef __attribute__((ext_vector_type(2))) unsigned int u32x2;
typedef unsigned short ushort_t;

#define NEG_BIG (-1e30f)

__device__ __forceinline__ float bf2f(unsigned int u) {
    union { unsigned int i; float f; } v; v.i = u << 16; return v.f;
}
__device__ __forceinline__ ushort_t f2bf(float f) {
    __hip_bfloat16 h = __float2bfloat16(f);
    return *reinterpret_cast<ushort_t*>(&h);
}

// ---------------------------------------------------------------------------
// Transpose fp32 W[K][N] -> bf16 Wt[N][K]
// ---------------------------------------------------------------------------
__global__ __launch_bounds__(256) void transpose_w(const float* __restrict__ W,
                                                   ushort_t* __restrict__ Wt,
                                                   int K, int N) {
    __shared__ ushort_t tile[64][65];
    int n0 = blockIdx.x * 64;
    int k0 = blockIdx.y * 64;
    int tid = threadIdx.x;
#pragma unroll
    for (int ii = 0; ii < 16; ii++) {
        int idx = tid + ii * 256;
        int r = idx >> 6, c = idx & 63;
        tile[r][c] = f2bf(W[(size_t)(k0 + r) * N + n0 + c]);
    }
    __syncthreads();
#pragma unroll
    for (int ii = 0; ii < 16; ii++) {
        int idx = tid + ii * 256;
        int r = idx >> 6, c = idx & 63;
        Wt[(size_t)(n0 + r) * K + k0 + c] = tile[c][r];
    }
}

// ---------------------------------------------------------------------------
// Load 8 consecutive elements at elem offset `off` as packed bf16x8.
// AF32: A is fp32 (convert inline); else A is bf16.
// ---------------------------------------------------------------------------
template <int AF32>
__device__ __forceinline__ u32x4 load8(const void* __restrict__ A, size_t off) {
    if (AF32) {
        const float* p = (const float*)A + off;
        f32x4 a = *(const f32x4*)p;
        f32x4 b = *(const f32x4*)(p + 4);
        u32x4 r;
        r.x = (unsigned)f2bf(a.x) | ((unsigned)f2bf(a.y) << 16);
        r.y = (unsigned)f2bf(a.z) | ((unsigned)f2bf(a.w) << 16);
        r.z = (unsigned)f2bf(b.x) | ((unsigned)f2bf(b.y) << 16);
        r.w = (unsigned)f2bf(b.z) | ((unsigned)f2bf(b.w) << 16);
        return r;
    } else {
        return *(const u32x4*)((const ushort_t*)A + off);
    }
}

// ---------------------------------------------------------------------------
// C[M][N] = A[M][K] @ Bt[N][K]^T  (bf16 MFMA, fp32 accum)
// 128x128 tile, BK=32, 4 waves 2x2, each wave 4x4 of mfma_f32_16x16x32_bf16.
// Layouts verified (R2 pipeline agreed bit-for-bit with scalar pipeline).
// ---------------------------------------------------------------------------
template <int AF32, int OF32>
__global__ __launch_bounds__(256) void gemm_bt(const void* __restrict__ A,
                                               const ushort_t* __restrict__ Bt,
                                               void* __restrict__ C,
                                               int M, int N, int K) {
    __shared__ ushort_t As[128][32];
    __shared__ ushort_t Bs[128][32];
    int tid  = threadIdx.x;
    int lane = tid & 63;
    int wave = tid >> 6;
    int m0 = blockIdx.y * 128;
    int n0 = blockIdx.x * 128;
    int wm = (wave >> 1) * 64;
    int wn = (wave & 1) * 64;
    int lrow = tid >> 2;         // 0..63
    int lcol = (tid & 3) * 8;    // 0,8,16,24

    f32x4 acc[4][4];
#pragma unroll
    for (int i = 0; i < 4; i++)
#pragma unroll
        for (int j = 0; j < 4; j++) acc[i][j] = (f32x4){0.f, 0.f, 0.f, 0.f};

    const int mrow = lane & 15;
    const int kq   = (lane >> 4) * 8;

    for (int k0 = 0; k0 < K; k0 += 32) {
        u32x4 a0 = load8<AF32>(A, (size_t)(m0 + lrow) * K + k0 + lcol);
        u32x4 a1 = load8<AF32>(A, (size_t)(m0 + 64 + lrow) * K + k0 + lcol);
        u32x4 b0 = *(const u32x4*)(Bt + (size_t)(n0 + lrow) * K + k0 + lcol);
        u32x4 b1 = *(const u32x4*)(Bt + (size_t)(n0 + 64 + lrow) * K + k0 + lcol);
        __syncthreads();
        *(u32x4*)&As[lrow][lcol]      = a0;
        *(u32x4*)&As[64 + lrow][lcol] = a1;
        *(u32x4*)&Bs[lrow][lcol]      = b0;
        *(u32x4*)&Bs[64 + lrow][lcol] = b1;
        __syncthreads();
        bf16x8 afr[4], bfr[4];
#pragma unroll
        for (int i = 0; i < 4; i++) afr[i] = *(const bf16x8*)&As[wm + i * 16 + mrow][kq];
#pragma unroll
        for (int j = 0; j < 4; j++) bfr[j] = *(const bf16x8*)&Bs[wn + j * 16 + mrow][kq];
#pragma unroll
        for (int i = 0; i < 4; i++)
#pragma unroll
            for (int j = 0; j < 4; j++)
                acc[i][j] = __builtin_amdgcn_mfma_f32_16x16x32_bf16(afr[i], bfr[j], acc[i][j], 0, 0, 0);
    }

    int crow = (lane >> 4) * 4;
    int ccol = lane & 15;
#pragma unroll
    for (int i = 0; i < 4; i++)
#pragma unroll
        for (int j = 0; j < 4; j++) {
            int col = n0 + wn + j * 16 + ccol;
#pragma unroll
            for (int r = 0; r < 4; r++) {
                int row = m0 + wm + i * 16 + crow + r;
                if (OF32) ((float*)C)[(size_t)row * N + col] = acc[i][j][r];
                else      ((ushort_t*)C)[(size_t)row * N + col] = f2bf(acc[i][j][r]);
            }
        }
}

// ---------------------------------------------------------------------------
// In-place RoPE on bf16 X[T][cols], head dim 64 (32 pairs/head)
// ---------------------------------------------------------------------------
__global__ void rope_kernel(ushort_t* __restrict__ X, int T, int cols) {
    int idx = blockIdx.x * blockDim.x + threadIdx.x;
    int ppr = cols >> 1;
    if (idx >= T * ppr) return;
    int t = idx / ppr;
    int j = idx - t * ppr;
    int i = j & 31;
    int col = ((j >> 5) << 6) + (i << 1);
    // inv_freq = theta^(-i/32); ln(500000) = 13.122363377404328
    float inv = expf(-(float)i * (13.122363377404328f / 32.0f));
    float ang = (float)t * inv;
    float c = cosf(ang), s = sinf(ang);
    size_t base = (size_t)t * cols + col;
    float x1 = bf2f((unsigned int)X[base]);
    float x2 = bf2f((unsigned int)X[base + 1]);
    X[base]     = f2bf(x1 * c - x2 * s);
    X[base + 1] = f2bf(x1 * s + x2 * c);
}

// ---------------------------------------------------------------------------
// Flash attention (causal, GQA 4:1). One block per (64-row Q tile, head).
// 64x64 K/V tiles in LDS (fp32, padded), 4x4 register blocking, online softmax.
// ---------------------------------------------------------------------------
__global__ __launch_bounds__(256) void attn_kernel(const ushort_t* __restrict__ Q,
                                                   const ushort_t* __restrict__ Kb,
                                                   const ushort_t* __restrict__ Vb,
                                                   ushort_t* __restrict__ Ob) {
    __shared__ float Qs[64][65];
    __shared__ float KPs[64][65];   // K tile, then reused for P tile
    __shared__ float Vs[64][65];
    int tid = threadIdx.x;
    int h  = blockIdx.y;
    int q0 = blockIdx.x * 64;
    int hk = h >> 2;
    int tr = tid >> 4, tc = tid & 15;
    int r4 = tr * 4, c4 = tc * 4;

    // load Q tile (bf16 -> f32)
#pragma unroll
    for (int ii = 0; ii < 4; ii++) {
        int e = (tid + ii * 256) * 4;
        int r = e >> 6, c = e & 63;
        u32x2 raw = *(const u32x2*)(Q + (size_t)(q0 + r) * D_MODEL + h * HD + c);
        Qs[r][c + 0] = bf2f(raw.x & 0xffffu);
        Qs[r][c + 1] = bf2f(raw.x >> 16);
        Qs[r][c + 2] = bf2f(raw.y & 0xffffu);
        Qs[r][c + 3] = bf2f(raw.y >> 16);
    }

    float m_i[4], l_i[4], o[4][4];
#pragma unroll
    for (int rl = 0; rl < 4; rl++) {
        m_i[rl] = NEG_BIG;
        l_i[rl] = 0.f;
#pragma unroll
        for (int dl = 0; dl < 4; dl++) o[rl][dl] = 0.f;
    }

    int ntiles = (q0 >> 6) + 1;
    for (int jt = 0; jt < ntiles; jt++) {
        int j0 = jt * 64;
        __syncthreads();   // protect KPs/Vs from previous iteration's readers
#pragma unroll
        for (int ii = 0; ii < 4; ii++) {
            int e = (tid + ii * 256) * 4;
            int r = e >> 6, c = e & 63;
            u32x2 kr = *(const u32x2*)(Kb + (size_t)(j0 + r) * DIM_KV + hk * HD + c);
            u32x2 vr = *(const u32x2*)(Vb + (size_t)(j0 + r) * DIM_KV + hk * HD + c);
            KPs[r][c + 0] = bf2f(kr.x & 0xffffu);
            KPs[r][c + 1] = bf2f(kr.x >> 16);
            KPs[r][c + 2] = bf2f(kr.y & 0xffffu);
            KPs[r][c + 3] = bf2f(kr.y >> 16);
            Vs[r][c + 0] = bf2f(vr.x & 0xffffu);
            Vs[r][c + 1] = bf2f(vr.x >> 16);
            Vs[r][c + 2] = bf2f(vr.y & 0xffffu);
            Vs[r][c + 3] = bf2f(vr.y >> 16);
        }
        __syncthreads();

        float s[4][4];
#pragma unroll
        for (int rl = 0; rl < 4; rl++)
#pragma unroll
            for (int cl = 0; cl < 4; cl++) s[rl][cl] = 0.f;
#pragma unroll 8
        for (int d = 0; d < 64; d++) {
            float qv[4], kv[4];
#pragma unroll
            for (int rl = 0; rl < 4; rl++) qv[rl] = Qs[r4 + rl][d];
#pragma unroll
            for (int cl = 0; cl < 4; cl++) kv[cl] = KPs[c4 + cl][d];
#pragma unroll
            for (int rl = 0; rl < 4; rl++)
#pragma unroll
                for (int cl = 0; cl < 4; cl++) s[rl][cl] += qv[rl] * kv[cl];
        }

#pragma unroll
        for (int rl = 0; rl < 4; rl++)
#pragma unroll
            for (int cl = 0; cl < 4; cl++) {
                float sv = s[rl][cl] * 0.125f;
                if (j0 + c4 + cl > q0 + r4 + rl) sv = NEG_BIG;
                s[rl][cl] = sv;
            }

        float p[4][4];
#pragma unroll
        for (int rl = 0; rl < 4; rl++) {
            float mt = fmaxf(fmaxf(s[rl][0], s[rl][1]), fmaxf(s[rl][2], s[rl][3]));
#pragma unroll
            for (int off = 1; off < 16; off <<= 1) mt = fmaxf(mt, __shfl_xor(mt, off, 64));
            float mn = fmaxf(m_i[rl], mt);
            float alpha = __expf(m_i[rl] - mn);
            m_i[rl] = mn;
            float sum = 0.f;
#pragma unroll
            for (int cl = 0; cl < 4; cl++) {
                p[rl][cl] = __expf(s[rl][cl] - mn);
                sum += p[rl][cl];
            }
#pragma unroll
            for (int off = 1; off < 16; off <<= 1) sum += __shfl_xor(sum, off, 64);
            l_i[rl] = l_i[rl] * alpha + sum;
#pragma unroll
            for (int dl = 0; dl < 4; dl++) o[rl][dl] *= alpha;
        }

        __syncthreads();   // all K reads done; reuse KPs for P
#pragma unroll
        for (int rl = 0; rl < 4; rl++)
#pragma unroll
            for (int cl = 0; cl < 4; cl++) KPs[r4 + rl][c4 + cl] = p[rl][cl];
        __syncthreads();

#pragma unroll 8
        for (int c = 0; c < 64; c++) {
            float pv[4], vv[4];
#pragma unroll
            for (int rl = 0; rl < 4; rl++) pv[rl] = KPs[r4 + rl][c];
#pragma unroll
            for (int dl = 0; dl < 4; dl++) vv[dl] = Vs[c][c4 + dl];
#pragma unroll
            for (int rl = 0; rl < 4; rl++)
#pragma unroll
                for (int dl = 0; dl < 4; dl++) o[rl][dl] += pv[rl] * vv[dl];
        }
    }

#pragma unroll
    for (int rl = 0; rl < 4; rl++) {
        float inv = (l_i[rl] > 0.f) ? 1.0f / l_i[rl] : 0.f;
#pragma unroll
        for (int dl = 0; dl < 4; dl++) {
            Ob[(size_t)(q0 + r4 + rl) * D_MODEL + h * HD + c4 + dl] = f2bf(o[rl][dl] * inv);
        }
    }
}

// ---------------------------------------------------------------------------
extern "C" void kernel_launch(void* const* d_in, const int* in_sizes, int n_in,
                              void* d_out, int out_size, void* d_ws, size_t ws_size,
                              hipStream_t stream) {
    const float* q_embs = (const float*)d_in[0];
    const float* k_embs = (const float*)d_in[1];
    const float* v_embs = (const float*)d_in[2];
    const float* w_q = (const float*)d_in[3];
    const float* w_k = (const float*)d_in[4];
    const float* w_v = (const float*)d_in[5];
    const float* w_o = (const float*)d_in[6];
    float* out = (float*)d_out;

    const size_t M1 = (size_t)1024 * 1024;
    ushort_t* base = (ushort_t*)d_ws;
    // bf16 workspace, 32 MB total:
    //   [0,4M)  wqT, later aliased by woT (wqT dead after Q-proj GEMM)
    //   [4M,5M) wkT   [5M,6M) wvT
    //   [6M,10M) Qb   [10M,11M) Kb   [11M,12M) Vb
    //   [12M,16M) Ab
    ushort_t* wqT = base + 0 * M1;
    ushort_t* woT = base + 0 * M1;   // alias, stream-ordered after Q GEMM
    ushort_t* wkT = base + 4 * M1;
    ushort_t* wvT = base + 5 * M1;
    ushort_t* Qb  = base + 6 * M1;
    ushort_t* Kb  = base + 10 * M1;
    ushort_t* Vb  = base + 11 * M1;
    ushort_t* Ab  = base + 12 * M1;

    dim3 blk(256);
    transpose_w<<<dim3(32, 32), blk, 0, stream>>>(w_q, wqT, 2048, 2048);
    transpose_w<<<dim3(8, 32), blk, 0, stream>>>(w_k, wkT, 2048, 512);
    transpose_w<<<dim3(8, 32), blk, 0, stream>>>(w_v, wvT, 2048, 512);

    gemm_bt<1, 0><<<dim3(16, 16), blk, 0, stream>>>(q_embs, wqT, Qb, 2048, 2048, 2048);
    gemm_bt<1, 0><<<dim3(4, 16), blk, 0, stream>>>(k_embs, wkT, Kb, 2048, 512, 2048);
    gemm_bt<1, 0><<<dim3(4, 16), blk, 0, stream>>>(v_embs, wvT, Vb, 2048, 512, 2048);

    // w_o transpose AFTER Q GEMM (woT aliases wqT)
    transpose_w<<<dim3(32, 32), blk, 0, stream>>>(w_o, woT, 2048, 2048);

    rope_kernel<<<(2048 * 1024 + 255) / 256, blk, 0, stream>>>(Qb, 2048, 2048);
    rope_kernel<<<(2048 * 256 + 255) / 256, blk, 0, stream>>>(Kb, 2048, 512);

    attn_kernel<<<dim3(32, 32), blk, 0, stream>>>(Qb, Kb, Vb, Ab);

    gemm_bt<0, 1><<<dim3(16, 16), blk, 0, stream>>>(Ab, woT, out, 2048, 2048, 2048);
}

// Round 7
// 535.242 us; speedup vs baseline: 8.0945x; 2.1084x over previous
//
#include <hip/hip_runtime.h>
#include <hip/hip_bf16.h>
#include <cstdint>

#define D_MODEL 2048
#define T_SEQ   2048
#define NQH     32
#define NKVH    8
#define HD      64
#define DIM_KV  512

typedef __attribute__((ext_vector_type(8))) __bf16 bf16x8;
typedef __attribute__((ext_vector_type(4))) float  f32x4;
typedef __attribute__((ext_vector_type(4))) unsigned int u32x4;
typedef unsigned short ushort_t;

#define NEG_BIG (-1e30f)

__device__ __forceinline__ float bf2f(unsigned int u) {
    union { unsigned int i; float f; } v; v.i = u << 16; return v.f;
}
__device__ __forceinline__ ushort_t f2bf(float f) {
    __hip_bfloat16 h = __float2bfloat16(f);
    return *reinterpret_cast<ushort_t*>(&h);
}

// ---------------------------------------------------------------------------
// Transpose fp32 W[K][N] -> bf16 Wt[N][K]
// ---------------------------------------------------------------------------
__global__ __launch_bounds__(256) void transpose_w(const float* __restrict__ W,
                                                   ushort_t* __restrict__ Wt,
                                                   int K, int N) {
    __shared__ ushort_t tile[64][65];
    int n0 = blockIdx.x * 64;
    int k0 = blockIdx.y * 64;
    int tid = threadIdx.x;
#pragma unroll
    for (int ii = 0; ii < 16; ii++) {
        int idx = tid + ii * 256;
        int r = idx >> 6, c = idx & 63;
        tile[r][c] = f2bf(W[(size_t)(k0 + r) * N + n0 + c]);
    }
    __syncthreads();
#pragma unroll
    for (int ii = 0; ii < 16; ii++) {
        int idx = tid + ii * 256;
        int r = idx >> 6, c = idx & 63;
        Wt[(size_t)(n0 + r) * K + k0 + c] = tile[c][r];
    }
}

// ---------------------------------------------------------------------------
// Transpose bf16 V[T][DIM_KV] -> Vt[NKVH][HD][T]  (per-head d-major)
// grid: (T/64, NKVH)
// ---------------------------------------------------------------------------
__global__ __launch_bounds__(256) void transpose_v(const ushort_t* __restrict__ V,
                                                   ushort_t* __restrict__ Vt) {
    __shared__ ushort_t tile[64][65];
    int h  = blockIdx.y;
    int j0 = blockIdx.x * 64;
    int tid = threadIdx.x;
#pragma unroll
    for (int ii = 0; ii < 16; ii++) {
        int idx = tid + ii * 256;
        int r = idx >> 6, c = idx & 63;       // r = j offset, c = d offset
        tile[r][c] = V[(size_t)(j0 + r) * DIM_KV + h * HD + c];
    }
    __syncthreads();
#pragma unroll
    for (int ii = 0; ii < 16; ii++) {
        int idx = tid + ii * 256;
        int r = idx >> 6, c = idx & 63;       // r = d, c = j offset
        Vt[((size_t)h * HD + r) * T_SEQ + j0 + c] = tile[c][r];
    }
}

// ---------------------------------------------------------------------------
// Load 8 consecutive elements at elem offset `off` as packed bf16x8.
// ---------------------------------------------------------------------------
template <int AF32>
__device__ __forceinline__ u32x4 load8(const void* __restrict__ A, size_t off) {
    if (AF32) {
        const float* p = (const float*)A + off;
        f32x4 a = *(const f32x4*)p;
        f32x4 b = *(const f32x4*)(p + 4);
        u32x4 r;
        r.x = (unsigned)f2bf(a.x) | ((unsigned)f2bf(a.y) << 16);
        r.y = (unsigned)f2bf(a.z) | ((unsigned)f2bf(a.w) << 16);
        r.z = (unsigned)f2bf(b.x) | ((unsigned)f2bf(b.y) << 16);
        r.w = (unsigned)f2bf(b.z) | ((unsigned)f2bf(b.w) << 16);
        return r;
    } else {
        return *(const u32x4*)((const ushort_t*)A + off);
    }
}

// ---------------------------------------------------------------------------
// C[M][N] = A[M][K] @ Bt[N][K]^T  (bf16 MFMA, fp32 accum) — verified layouts
// ---------------------------------------------------------------------------
template <int AF32, int OF32>
__global__ __launch_bounds__(256) void gemm_bt(const void* __restrict__ A,
                                               const ushort_t* __restrict__ Bt,
                                               void* __restrict__ C,
                                               int M, int N, int K) {
    __shared__ ushort_t As[128][32];
    __shared__ ushort_t Bs[128][32];
    int tid  = threadIdx.x;
    int lane = tid & 63;
    int wave = tid >> 6;
    int m0 = blockIdx.y * 128;
    int n0 = blockIdx.x * 128;
    int wm = (wave >> 1) * 64;
    int wn = (wave & 1) * 64;
    int lrow = tid >> 2;
    int lcol = (tid & 3) * 8;

    f32x4 acc[4][4];
#pragma unroll
    for (int i = 0; i < 4; i++)
#pragma unroll
        for (int j = 0; j < 4; j++) acc[i][j] = (f32x4){0.f, 0.f, 0.f, 0.f};

    const int mrow = lane & 15;
    const int kq   = (lane >> 4) * 8;

    for (int k0 = 0; k0 < K; k0 += 32) {
        u32x4 a0 = load8<AF32>(A, (size_t)(m0 + lrow) * K + k0 + lcol);
        u32x4 a1 = load8<AF32>(A, (size_t)(m0 + 64 + lrow) * K + k0 + lcol);
        u32x4 b0 = *(const u32x4*)(Bt + (size_t)(n0 + lrow) * K + k0 + lcol);
        u32x4 b1 = *(const u32x4*)(Bt + (size_t)(n0 + 64 + lrow) * K + k0 + lcol);
        __syncthreads();
        *(u32x4*)&As[lrow][lcol]      = a0;
        *(u32x4*)&As[64 + lrow][lcol] = a1;
        *(u32x4*)&Bs[lrow][lcol]      = b0;
        *(u32x4*)&Bs[64 + lrow][lcol] = b1;
        __syncthreads();
        bf16x8 afr[4], bfr[4];
#pragma unroll
        for (int i = 0; i < 4; i++) afr[i] = *(const bf16x8*)&As[wm + i * 16 + mrow][kq];
#pragma unroll
        for (int j = 0; j < 4; j++) bfr[j] = *(const bf16x8*)&Bs[wn + j * 16 + mrow][kq];
#pragma unroll
        for (int i = 0; i < 4; i++)
#pragma unroll
            for (int j = 0; j < 4; j++)
                acc[i][j] = __builtin_amdgcn_mfma_f32_16x16x32_bf16(afr[i], bfr[j], acc[i][j], 0, 0, 0);
    }

    int crow = (lane >> 4) * 4;
    int ccol = lane & 15;
#pragma unroll
    for (int i = 0; i < 4; i++)
#pragma unroll
        for (int j = 0; j < 4; j++) {
            int col = n0 + wn + j * 16 + ccol;
#pragma unroll
            for (int r = 0; r < 4; r++) {
                int row = m0 + wm + i * 16 + crow + r;
                if (OF32) ((float*)C)[(size_t)row * N + col] = acc[i][j][r];
                else      ((ushort_t*)C)[(size_t)row * N + col] = f2bf(acc[i][j][r]);
            }
        }
}

// ---------------------------------------------------------------------------
// In-place RoPE on bf16 X[T][cols], head dim 64 (32 pairs/head)
// ---------------------------------------------------------------------------
__global__ void rope_kernel(ushort_t* __restrict__ X, int T, int cols) {
    int idx = blockIdx.x * blockDim.x + threadIdx.x;
    int ppr = cols >> 1;
    if (idx >= T * ppr) return;
    int t = idx / ppr;
    int j = idx - t * ppr;
    int i = j & 31;
    int col = ((j >> 5) << 6) + (i << 1);
    float inv = expf(-(float)i * (13.122363377404328f / 32.0f));
    float ang = (float)t * inv;
    float c = cosf(ang), s = sinf(ang);
    size_t base = (size_t)t * cols + col;
    float x1 = bf2f((unsigned int)X[base]);
    float x2 = bf2f((unsigned int)X[base + 1]);
    X[base]     = f2bf(x1 * c - x2 * s);
    X[base + 1] = f2bf(x1 * s + x2 * c);
}

// ---------------------------------------------------------------------------
// MFMA flash attention (causal, GQA 4:1).
// Block = (64-row Q tile, q-head); 4 waves, wave w owns S-strip rows
// [w*16, w*16+16). QK^T and PV on mfma_f32_16x16x32_bf16 with the verified
// gemm_bt fragment layouts; P converts C-layout -> A-layout via LDS.
// Vt is pre-transposed: Vt[h][d][j].
// ---------------------------------------------------------------------------
__global__ __launch_bounds__(256) void attn_mfma(const ushort_t* __restrict__ Q,
                                                 const ushort_t* __restrict__ Kb,
                                                 const ushort_t* __restrict__ Vt,
                                                 ushort_t* __restrict__ Ob) {
    __shared__ ushort_t Qs[64][72];   // [q-row][d]     (pitch 72: 16B-aligned b128)
    __shared__ ushort_t Ks[64][72];   // [k-row][d]
    __shared__ ushort_t Vs[64][72];   // [d][k-row]  (V^T tile)
    __shared__ ushort_t Ps[64][72];   // [q-row][k-row]; wave w rows [w*16,w*16+16)

    int tid  = threadIdx.x;
    int lane = tid & 63;
    int wave = tid >> 6;
    int h    = blockIdx.y;
    int hk   = h >> 2;
    int qt   = (int)gridDim.x - 1 - (int)blockIdx.x;   // long blocks first
    int q0   = qt * 64;
    int l15  = lane & 15;
    int quad = lane >> 4;
    int kq   = quad * 8;

    // ---- stage Q tile (64 x 64) ----
    {
        int r = tid >> 3;              // 0..31
        int c = (tid & 7) * 8;         // 0..56
        *(u32x4*)&Qs[r][c]      = *(const u32x4*)(Q + (size_t)(q0 + r) * D_MODEL + h * HD + c);
        *(u32x4*)&Qs[r + 32][c] = *(const u32x4*)(Q + (size_t)(q0 + r + 32) * D_MODEL + h * HD + c);
    }
    __syncthreads();
    // hoist Q A-frags (invariant over K tiles)
    bf16x8 aq0 = *(const bf16x8*)&Qs[wave * 16 + l15][kq];
    bf16x8 aq1 = *(const bf16x8*)&Qs[wave * 16 + l15][kq + 32];

    f32x4 oacc[4];
    float m_i[4], l_i[4];
#pragma unroll
    for (int i = 0; i < 4; i++) {
        oacc[i] = (f32x4){0.f, 0.f, 0.f, 0.f};
        m_i[i] = NEG_BIG;
        l_i[i] = 0.f;
    }

    int ntiles = qt + 1;
    for (int jt = 0; jt < ntiles; jt++) {
        int j0 = jt * 64;
        __syncthreads();   // prev iteration's PV reads done before overwrite
        {
            int r = tid >> 3;
            int c = (tid & 7) * 8;
            *(u32x4*)&Ks[r][c]      = *(const u32x4*)(Kb + (size_t)(j0 + r) * DIM_KV + hk * HD + c);
            *(u32x4*)&Ks[r + 32][c] = *(const u32x4*)(Kb + (size_t)(j0 + r + 32) * DIM_KV + hk * HD + c);
            *(u32x4*)&Vs[r][c]      = *(const u32x4*)(Vt + ((size_t)hk * HD + r) * T_SEQ + j0 + c);
            *(u32x4*)&Vs[r + 32][c] = *(const u32x4*)(Vt + ((size_t)hk * HD + r + 32) * T_SEQ + j0 + c);
        }
        __syncthreads();

        // ---- S strip = Q_strip @ K^T : 4 col-tiles x 2 K-halves ----
        f32x4 sacc[4];
#pragma unroll
        for (int ct = 0; ct < 4; ct++) {
            bf16x8 bk0 = *(const bf16x8*)&Ks[ct * 16 + l15][kq];
            bf16x8 bk1 = *(const bf16x8*)&Ks[ct * 16 + l15][kq + 32];
            sacc[ct] = __builtin_amdgcn_mfma_f32_16x16x32_bf16(aq0, bk0, (f32x4){0.f,0.f,0.f,0.f}, 0, 0, 0);
            sacc[ct] = __builtin_amdgcn_mfma_f32_16x16x32_bf16(aq1, bk1, sacc[ct], 0, 0, 0);
        }

        // ---- scale + mask + online softmax ----
        // C layout: lane holds rows y = quad*4+reg (strip-local), col x = ct*16+l15
        bool diag = (jt == ntiles - 1);
#pragma unroll
        for (int reg = 0; reg < 4; reg++) {
            int y = quad * 4 + reg;            // strip-local row
            float s[4];
#pragma unroll
            for (int ct = 0; ct < 4; ct++) {
                float sv = sacc[ct][reg] * 0.125f;
                if (diag && (ct * 16 + l15 > wave * 16 + y)) sv = NEG_BIG;
                s[ct] = sv;
            }
            float mt = fmaxf(fmaxf(s[0], s[1]), fmaxf(s[2], s[3]));
#pragma unroll
            for (int off = 1; off < 16; off <<= 1) mt = fmaxf(mt, __shfl_xor(mt, off, 64));
            float mn    = fmaxf(m_i[reg], mt);
            float alpha = __expf(m_i[reg] - mn);
            m_i[reg] = mn;
            float sum = 0.f;
#pragma unroll
            for (int ct = 0; ct < 4; ct++) {
                float p = __expf(s[ct] - mn);
                sum += p;
                Ps[wave * 16 + y][ct * 16 + l15] = f2bf(p);
            }
#pragma unroll
            for (int off = 1; off < 16; off <<= 1) sum += __shfl_xor(sum, off, 64);
            l_i[reg] = l_i[reg] * alpha + sum;
#pragma unroll
            for (int dt = 0; dt < 4; dt++) oacc[dt][reg] *= alpha;
        }
        __syncthreads();   // Ps visible to whole wave's frag reads

        // ---- O strip += P_strip @ V : A from Ps, B from Vs (=V^T) ----
        bf16x8 ap0 = *(const bf16x8*)&Ps[wave * 16 + l15][kq];
        bf16x8 ap1 = *(const bf16x8*)&Ps[wave * 16 + l15][kq + 32];
#pragma unroll
        for (int dt = 0; dt < 4; dt++) {
            bf16x8 bv0 = *(const bf16x8*)&Vs[dt * 16 + l15][kq];
            bf16x8 bv1 = *(const bf16x8*)&Vs[dt * 16 + l15][kq + 32];
            oacc[dt] = __builtin_amdgcn_mfma_f32_16x16x32_bf16(ap0, bv0, oacc[dt], 0, 0, 0);
            oacc[dt] = __builtin_amdgcn_mfma_f32_16x16x32_bf16(ap1, bv1, oacc[dt], 0, 0, 0);
        }
    }

    // ---- epilogue: normalize, write O (C layout) ----
#pragma unroll
    for (int reg = 0; reg < 4; reg++) {
        float inv = (l_i[reg] > 0.f) ? 1.0f / l_i[reg] : 0.f;
        int row = q0 + wave * 16 + quad * 4 + reg;
#pragma unroll
        for (int dt = 0; dt < 4; dt++) {
            Ob[(size_t)row * D_MODEL + h * HD + dt * 16 + l15] = f2bf(oacc[dt][reg] * inv);
        }
    }
}

// ---------------------------------------------------------------------------
extern "C" void kernel_launch(void* const* d_in, const int* in_sizes, int n_in,
                              void* d_out, int out_size, void* d_ws, size_t ws_size,
                              hipStream_t stream) {
    const float* q_embs = (const float*)d_in[0];
    const float* k_embs = (const float*)d_in[1];
    const float* v_embs = (const float*)d_in[2];
    const float* w_q = (const float*)d_in[3];
    const float* w_k = (const float*)d_in[4];
    const float* w_v = (const float*)d_in[5];
    const float* w_o = (const float*)d_in[6];
    float* out = (float*)d_out;

    const size_t M1 = (size_t)1024 * 1024;
    ushort_t* base = (ushort_t*)d_ws;
    // bf16 workspace, 32 MB total:
    //   [0,4M)   wqT -> later woT (wqT dead after Q GEMM)
    //   [4M,5M)  wkT -> later VtG (wkT dead after K GEMM)
    //   [5M,6M)  wvT
    //   [6M,10M) Qb   [10M,11M) Kb   [11M,12M) Vb   [12M,16M) Ab
    ushort_t* wqT = base + 0 * M1;
    ushort_t* woT = base + 0 * M1;
    ushort_t* wkT = base + 4 * M1;
    ushort_t* VtG = base + 4 * M1;
    ushort_t* wvT = base + 5 * M1;
    ushort_t* Qb  = base + 6 * M1;
    ushort_t* Kb  = base + 10 * M1;
    ushort_t* Vb  = base + 11 * M1;
    ushort_t* Ab  = base + 12 * M1;

    dim3 blk(256);
    transpose_w<<<dim3(32, 32), blk, 0, stream>>>(w_q, wqT, 2048, 2048);
    transpose_w<<<dim3(8, 32), blk, 0, stream>>>(w_k, wkT, 2048, 512);
    transpose_w<<<dim3(8, 32), blk, 0, stream>>>(w_v, wvT, 2048, 512);

    gemm_bt<1, 0><<<dim3(16, 16), blk, 0, stream>>>(q_embs, wqT, Qb, 2048, 2048, 2048);
    gemm_bt<1, 0><<<dim3(4, 16), blk, 0, stream>>>(k_embs, wkT, Kb, 2048, 512, 2048);
    gemm_bt<1, 0><<<dim3(4, 16), blk, 0, stream>>>(v_embs, wvT, Vb, 2048, 512, 2048);

    // w_o transpose AFTER Q GEMM (woT aliases wqT)
    transpose_w<<<dim3(32, 32), blk, 0, stream>>>(w_o, woT, 2048, 2048);

    rope_kernel<<<(2048 * 1024 + 255) / 256, blk, 0, stream>>>(Qb, 2048, 2048);
    rope_kernel<<<(2048 * 256 + 255) / 256, blk, 0, stream>>>(Kb, 2048, 512);

    // V^T for PV MFMA B-operand (VtG aliases wkT, dead after K GEMM)
    transpose_v<<<dim3(32, 8), blk, 0, stream>>>(Vb, VtG);

    attn_mfma<<<dim3(32, 32), blk, 0, stream>>>(Qb, Kb, VtG, Ab);

    gemm_bt<0, 1><<<dim3(16, 16), blk, 0, stream>>>(Ab, woT, out, 2048, 2048, 2048);
}

// Round 8
// 415.134 us; speedup vs baseline: 10.4365x; 1.2893x over previous
//
#include <hip/hip_runtime.h>
#include <hip/hip_bf16.h>
#include <cstdint>

#define D_MODEL 2048
#define T_SEQ   2048
#define NQH     32
#define NKVH    8
#define HD      64
#define DIM_KV  512

typedef __attribute__((ext_vector_type(8))) __bf16 bf16x8;
typedef __attribute__((ext_vector_type(4))) float  f32x4;
typedef __attribute__((ext_vector_type(4))) unsigned int u32x4;
typedef unsigned short ushort_t;

#define NEG_BIG (-1e30f)
#define AS1 __attribute__((address_space(1)))
#define AS3 __attribute__((address_space(3)))

__device__ __forceinline__ float bf2f(unsigned int u) {
    union { unsigned int i; float f; } v; v.i = u << 16; return v.f;
}
__device__ __forceinline__ ushort_t f2bf(float f) {
    __hip_bfloat16 h = __float2bfloat16(f);
    return *reinterpret_cast<ushort_t*>(&h);
}
// async global->LDS, 16B per lane; LDS dst must be wave-uniform base + lane*16
__device__ __forceinline__ void gll16(const ushort_t* g, ushort_t* l) {
    __builtin_amdgcn_global_load_lds((const AS1 void*)g, (AS3 void*)l, 16, 0, 0);
}

// ---------------------------------------------------------------------------
// fp32 -> bf16 elementwise convert (8 elems/thread)
// ---------------------------------------------------------------------------
__global__ __launch_bounds__(256) void conv_bf16(const float* __restrict__ X,
                                                 ushort_t* __restrict__ E, int n) {
    int i8 = (blockIdx.x * 256 + threadIdx.x) * 8;
    if (i8 >= n) return;
    f32x4 a = *(const f32x4*)(X + i8);
    f32x4 b = *(const f32x4*)(X + i8 + 4);
    u32x4 r;
    r.x = (unsigned)f2bf(a.x) | ((unsigned)f2bf(a.y) << 16);
    r.y = (unsigned)f2bf(a.z) | ((unsigned)f2bf(a.w) << 16);
    r.z = (unsigned)f2bf(b.x) | ((unsigned)f2bf(b.y) << 16);
    r.w = (unsigned)f2bf(b.z) | ((unsigned)f2bf(b.w) << 16);
    *(u32x4*)(E + i8) = r;
}

// ---------------------------------------------------------------------------
// Transpose fp32 W[K][N] -> bf16 Wt[N][K]
// ---------------------------------------------------------------------------
__global__ __launch_bounds__(256) void transpose_w(const float* __restrict__ W,
                                                   ushort_t* __restrict__ Wt,
                                                   int K, int N) {
    __shared__ ushort_t tile[64][65];
    int n0 = blockIdx.x * 64;
    int k0 = blockIdx.y * 64;
    int tid = threadIdx.x;
#pragma unroll
    for (int ii = 0; ii < 16; ii++) {
        int idx = tid + ii * 256;
        int r = idx >> 6, c = idx & 63;
        tile[r][c] = f2bf(W[(size_t)(k0 + r) * N + n0 + c]);
    }
    __syncthreads();
#pragma unroll
    for (int ii = 0; ii < 16; ii++) {
        int idx = tid + ii * 256;
        int r = idx >> 6, c = idx & 63;
        Wt[(size_t)(n0 + r) * K + k0 + c] = tile[c][r];
    }
}

// ---------------------------------------------------------------------------
// Transpose bf16 V[T][DIM_KV] -> Vt[NKVH][HD][T]
// ---------------------------------------------------------------------------
__global__ __launch_bounds__(256) void transpose_v(const ushort_t* __restrict__ V,
                                                   ushort_t* __restrict__ Vt) {
    __shared__ ushort_t tile[64][65];
    int h  = blockIdx.y;
    int j0 = blockIdx.x * 64;
    int tid = threadIdx.x;
#pragma unroll
    for (int ii = 0; ii < 16; ii++) {
        int idx = tid + ii * 256;
        int r = idx >> 6, c = idx & 63;
        tile[r][c] = V[(size_t)(j0 + r) * DIM_KV + h * HD + c];
    }
    __syncthreads();
#pragma unroll
    for (int ii = 0; ii < 16; ii++) {
        int idx = tid + ii * 256;
        int r = idx >> 6, c = idx & 63;
        Vt[((size_t)h * HD + r) * T_SEQ + j0 + c] = tile[c][r];
    }
}

// ---------------------------------------------------------------------------
// 128x128 tile GEMM, m97 structure (global_load_lds width=16), bf16 in,
// fp32 MFMA accum. C[M][N] = A[M][K] @ Bt[N][K]^T.
// ---------------------------------------------------------------------------
template <int OF32>
__global__ __launch_bounds__(256) void gemm128(const ushort_t* __restrict__ A,
                                               const ushort_t* __restrict__ Bt,
                                               void* __restrict__ C,
                                               int M, int N, int K) {
    __shared__ ushort_t As[128][32];
    __shared__ ushort_t Bs[128][32];
    int tid  = threadIdx.x;
    int lane = tid & 63;
    int wave = tid >> 6;
    int m0 = blockIdx.y * 128;
    int n0 = blockIdx.x * 128;
    int wm = (wave >> 1) * 64;
    int wn = (wave & 1) * 64;
    int lrow = tid >> 2;         // 0..63
    int lcol = (tid & 3) * 8;    // 0,8,16,24

    f32x4 acc[4][4];
#pragma unroll
    for (int i = 0; i < 4; i++)
#pragma unroll
        for (int j = 0; j < 4; j++) acc[i][j] = (f32x4){0.f, 0.f, 0.f, 0.f};

    const int mrow = lane & 15;
    const int kq   = (lane >> 4) * 8;

    for (int k0 = 0; k0 < K; k0 += 32) {
        __syncthreads();   // readers of previous tile done
        gll16(A  + (size_t)(m0 + lrow) * K + k0 + lcol,      &As[lrow][lcol]);
        gll16(A  + (size_t)(m0 + 64 + lrow) * K + k0 + lcol, &As[64 + lrow][lcol]);
        gll16(Bt + (size_t)(n0 + lrow) * K + k0 + lcol,      &Bs[lrow][lcol]);
        gll16(Bt + (size_t)(n0 + 64 + lrow) * K + k0 + lcol, &Bs[64 + lrow][lcol]);
        __syncthreads();   // compiler drains vmcnt before barrier
        bf16x8 afr[4], bfr[4];
#pragma unroll
        for (int i = 0; i < 4; i++) afr[i] = *(const bf16x8*)&As[wm + i * 16 + mrow][kq];
#pragma unroll
        for (int j = 0; j < 4; j++) bfr[j] = *(const bf16x8*)&Bs[wn + j * 16 + mrow][kq];
#pragma unroll
        for (int i = 0; i < 4; i++)
#pragma unroll
            for (int j = 0; j < 4; j++)
                acc[i][j] = __builtin_amdgcn_mfma_f32_16x16x32_bf16(afr[i], bfr[j], acc[i][j], 0, 0, 0);
    }

    int crow = (lane >> 4) * 4;
    int ccol = lane & 15;
#pragma unroll
    for (int i = 0; i < 4; i++)
#pragma unroll
        for (int j = 0; j < 4; j++) {
            int col = n0 + wn + j * 16 + ccol;
#pragma unroll
            for (int r = 0; r < 4; r++) {
                int row = m0 + wm + i * 16 + crow + r;
                if (OF32) ((float*)C)[(size_t)row * N + col] = acc[i][j][r];
                else      ((ushort_t*)C)[(size_t)row * N + col] = f2bf(acc[i][j][r]);
            }
        }
}

// ---------------------------------------------------------------------------
// 64x64 tile GEMM (for N=512 K/V projections: grid 8x32 = 256 blocks).
// 4 waves 2x2, each wave 2x2 of 16x16x32 MFMA.
// ---------------------------------------------------------------------------
__global__ __launch_bounds__(256) void gemm64(const ushort_t* __restrict__ A,
                                              const ushort_t* __restrict__ Bt,
                                              ushort_t* __restrict__ C,
                                              int M, int N, int K) {
    __shared__ ushort_t As[64][32];
    __shared__ ushort_t Bs[64][32];
    int tid  = threadIdx.x;
    int lane = tid & 63;
    int wave = tid >> 6;
    int m0 = blockIdx.y * 64;
    int n0 = blockIdx.x * 64;
    int wm = (wave >> 1) * 32;
    int wn = (wave & 1) * 32;
    int lrow = tid >> 2;
    int lcol = (tid & 3) * 8;

    f32x4 acc[2][2];
#pragma unroll
    for (int i = 0; i < 2; i++)
#pragma unroll
        for (int j = 0; j < 2; j++) acc[i][j] = (f32x4){0.f, 0.f, 0.f, 0.f};

    const int mrow = lane & 15;
    const int kq   = (lane >> 4) * 8;

    for (int k0 = 0; k0 < K; k0 += 32) {
        __syncthreads();
        gll16(A  + (size_t)(m0 + lrow) * K + k0 + lcol, &As[lrow][lcol]);
        gll16(Bt + (size_t)(n0 + lrow) * K + k0 + lcol, &Bs[lrow][lcol]);
        __syncthreads();
        bf16x8 afr[2], bfr[2];
#pragma unroll
        for (int i = 0; i < 2; i++) afr[i] = *(const bf16x8*)&As[wm + i * 16 + mrow][kq];
#pragma unroll
        for (int j = 0; j < 2; j++) bfr[j] = *(const bf16x8*)&Bs[wn + j * 16 + mrow][kq];
#pragma unroll
        for (int i = 0; i < 2; i++)
#pragma unroll
            for (int j = 0; j < 2; j++)
                acc[i][j] = __builtin_amdgcn_mfma_f32_16x16x32_bf16(afr[i], bfr[j], acc[i][j], 0, 0, 0);
    }

    int crow = (lane >> 4) * 4;
    int ccol = lane & 15;
#pragma unroll
    for (int i = 0; i < 2; i++)
#pragma unroll
        for (int j = 0; j < 2; j++) {
            int col = n0 + wn + j * 16 + ccol;
#pragma unroll
            for (int r = 0; r < 2 * 2; r++) {
                int row = m0 + wm + i * 16 + crow + (r & 3);
                if ((r & 3) == r) C[(size_t)row * N + col] = f2bf(acc[i][j][r]);
            }
        }
}

// ---------------------------------------------------------------------------
// In-place RoPE on bf16 X[T][cols], head dim 64 (32 pairs/head)
// ---------------------------------------------------------------------------
__global__ void rope_kernel(ushort_t* __restrict__ X, int T, int cols) {
    int idx = blockIdx.x * blockDim.x + threadIdx.x;
    int ppr = cols >> 1;
    if (idx >= T * ppr) return;
    int t = idx / ppr;
    int j = idx - t * ppr;
    int i = j & 31;
    int col = ((j >> 5) << 6) + (i << 1);
    float inv = expf(-(float)i * (13.122363377404328f / 32.0f));
    float ang = (float)t * inv;
    float c = cosf(ang), s = sinf(ang);
    size_t base = (size_t)t * cols + col;
    float x1 = bf2f((unsigned int)X[base]);
    float x2 = bf2f((unsigned int)X[base + 1]);
    X[base]     = f2bf(x1 * c - x2 * s);
    X[base + 1] = f2bf(x1 * s + x2 * c);
}

// ---------------------------------------------------------------------------
// MFMA flash attention (causal, GQA 4:1) with K/V register prefetch.
// Block = (64-row Q tile, q-head); wave w owns S-strip rows [w*16, w*16+16).
// Ps is written & read only by the owning wave -> no barrier needed there.
// ---------------------------------------------------------------------------
__global__ __launch_bounds__(256) void attn_mfma(const ushort_t* __restrict__ Q,
                                                 const ushort_t* __restrict__ Kb,
                                                 const ushort_t* __restrict__ Vt,
                                                 ushort_t* __restrict__ Ob) {
    __shared__ ushort_t Qs[64][72];
    __shared__ ushort_t Ks[64][72];
    __shared__ ushort_t Vs[64][72];   // V^T tile: [d][k-row]
    __shared__ ushort_t Ps[64][72];

    int tid  = threadIdx.x;
    int lane = tid & 63;
    int wave = tid >> 6;
    int h    = blockIdx.y;
    int hk   = h >> 2;
    int qt   = (int)gridDim.x - 1 - (int)blockIdx.x;   // long blocks first
    int q0   = qt * 64;
    int l15  = lane & 15;
    int quad = lane >> 4;
    int kq   = quad * 8;

    int r = tid >> 3;              // 0..31
    int c = (tid & 7) * 8;         // 0..56

    // ---- stage Q tile ----
    *(u32x4*)&Qs[r][c]      = *(const u32x4*)(Q + (size_t)(q0 + r) * D_MODEL + h * HD + c);
    *(u32x4*)&Qs[r + 32][c] = *(const u32x4*)(Q + (size_t)(q0 + r + 32) * D_MODEL + h * HD + c);
    __syncthreads();
    bf16x8 aq0 = *(const bf16x8*)&Qs[wave * 16 + l15][kq];
    bf16x8 aq1 = *(const bf16x8*)&Qs[wave * 16 + l15][kq + 32];

    f32x4 oacc[4];
    float m_i[4], l_i[4];
#pragma unroll
    for (int i = 0; i < 4; i++) {
        oacc[i] = (f32x4){0.f, 0.f, 0.f, 0.f};
        m_i[i] = NEG_BIG;
        l_i[i] = 0.f;
    }

    // ---- prefetch tile 0 into registers ----
    u32x4 kr0, kr1, vr0, vr1;
    {
        kr0 = *(const u32x4*)(Kb + (size_t)(0 + r) * DIM_KV + hk * HD + c);
        kr1 = *(const u32x4*)(Kb + (size_t)(32 + r) * DIM_KV + hk * HD + c);
        vr0 = *(const u32x4*)(Vt + ((size_t)hk * HD + r) * T_SEQ + 0 + c);
        vr1 = *(const u32x4*)(Vt + ((size_t)hk * HD + r + 32) * T_SEQ + 0 + c);
    }

    int ntiles = qt + 1;
    for (int jt = 0; jt < ntiles; jt++) {
        __syncthreads();   // all reads of previous Ks/Vs done
        *(u32x4*)&Ks[r][c]      = kr0;
        *(u32x4*)&Ks[r + 32][c] = kr1;
        *(u32x4*)&Vs[r][c]      = vr0;
        *(u32x4*)&Vs[r + 32][c] = vr1;
        __syncthreads();   // staged tile visible
        if (jt + 1 < ntiles) {   // issue next tile's loads; overlap compute
            int j0 = (jt + 1) * 64;
            kr0 = *(const u32x4*)(Kb + (size_t)(j0 + r) * DIM_KV + hk * HD + c);
            kr1 = *(const u32x4*)(Kb + (size_t)(j0 + r + 32) * DIM_KV + hk * HD + c);
            vr0 = *(const u32x4*)(Vt + ((size_t)hk * HD + r) * T_SEQ + j0 + c);
            vr1 = *(const u32x4*)(Vt + ((size_t)hk * HD + r + 32) * T_SEQ + j0 + c);
        }

        // ---- S strip = Q_strip @ K^T ----
        f32x4 sacc[4];
#pragma unroll
        for (int ct = 0; ct < 4; ct++) {
            bf16x8 bk0 = *(const bf16x8*)&Ks[ct * 16 + l15][kq];
            bf16x8 bk1 = *(const bf16x8*)&Ks[ct * 16 + l15][kq + 32];
            sacc[ct] = __builtin_amdgcn_mfma_f32_16x16x32_bf16(aq0, bk0, (f32x4){0.f,0.f,0.f,0.f}, 0, 0, 0);
            sacc[ct] = __builtin_amdgcn_mfma_f32_16x16x32_bf16(aq1, bk1, sacc[ct], 0, 0, 0);
        }

        // ---- scale + mask + online softmax ----
        bool diag = (jt == ntiles - 1);
#pragma unroll
        for (int reg = 0; reg < 4; reg++) {
            int y = quad * 4 + reg;
            float s[4];
#pragma unroll
            for (int ct = 0; ct < 4; ct++) {
                float sv = sacc[ct][reg] * 0.125f;
                if (diag && (ct * 16 + l15 > wave * 16 + y)) sv = NEG_BIG;
                s[ct] = sv;
            }
            float mt = fmaxf(fmaxf(s[0], s[1]), fmaxf(s[2], s[3]));
#pragma unroll
            for (int off = 1; off < 16; off <<= 1) mt = fmaxf(mt, __shfl_xor(mt, off, 64));
            float mn    = fmaxf(m_i[reg], mt);
            float alpha = __expf(m_i[reg] - mn);
            m_i[reg] = mn;
            float sum = 0.f;
#pragma unroll
            for (int ct = 0; ct < 4; ct++) {
                float p = __expf(s[ct] - mn);
                sum += p;
                Ps[wave * 16 + y][ct * 16 + l15] = f2bf(p);
            }
#pragma unroll
            for (int off = 1; off < 16; off <<= 1) sum += __shfl_xor(sum, off, 64);
            l_i[reg] = l_i[reg] * alpha + sum;
#pragma unroll
            for (int dt = 0; dt < 4; dt++) oacc[dt][reg] *= alpha;
        }
        // NO barrier: Ps rows [wave*16, wave*16+16) are wave-private;
        // compiler inserts the lgkmcnt wait for the write->read dependence.

        // ---- O strip += P_strip @ V ----
        bf16x8 ap0 = *(const bf16x8*)&Ps[wave * 16 + l15][kq];
        bf16x8 ap1 = *(const bf16x8*)&Ps[wave * 16 + l15][kq + 32];
#pragma unroll
        for (int dt = 0; dt < 4; dt++) {
            bf16x8 bv0 = *(const bf16x8*)&Vs[dt * 16 + l15][kq];
            bf16x8 bv1 = *(const bf16x8*)&Vs[dt * 16 + l15][kq + 32];
            oacc[dt] = __builtin_amdgcn_mfma_f32_16x16x32_bf16(ap0, bv0, oacc[dt], 0, 0, 0);
            oacc[dt] = __builtin_amdgcn_mfma_f32_16x16x32_bf16(ap1, bv1, oacc[dt], 0, 0, 0);
        }
    }

    // ---- epilogue ----
#pragma unroll
    for (int reg = 0; reg < 4; reg++) {
        float inv = (l_i[reg] > 0.f) ? 1.0f / l_i[reg] : 0.f;
        int row = q0 + wave * 16 + quad * 4 + reg;
#pragma unroll
        for (int dt = 0; dt < 4; dt++) {
            Ob[(size_t)row * D_MODEL + h * HD + dt * 16 + l15] = f2bf(oacc[dt][reg] * inv);
        }
    }
}

// ---------------------------------------------------------------------------
extern "C" void kernel_launch(void* const* d_in, const int* in_sizes, int n_in,
                              void* d_out, int out_size, void* d_ws, size_t ws_size,
                              hipStream_t stream) {
    const float* q_embs = (const float*)d_in[0];
    const float* k_embs = (const float*)d_in[1];
    const float* v_embs = (const float*)d_in[2];
    const float* w_q = (const float*)d_in[3];
    const float* w_k = (const float*)d_in[4];
    const float* w_v = (const float*)d_in[5];
    const float* w_o = (const float*)d_in[6];
    float* out = (float*)d_out;

    const size_t M1 = (size_t)1024 * 1024;
    ushort_t* base = (ushort_t*)d_ws;
    // bf16 workspace, exactly 32 MB (R2 evidence: >=32MB accessible):
    //   [0,4M)   E   (bf16 embeddings, reused q->k->v; later Ab)
    //   [4M,8M)  wqT -> later woT
    //   [8M,9M)  wkT -> later Vt
    //   [9M,10M) wvT
    //   [10M,14M) Qb  [14M,15M) Kb  [15M,16M) Vb
    ushort_t* E   = base + 0 * M1;
    ushort_t* Ab  = base + 0 * M1;
    ushort_t* wqT = base + 4 * M1;
    ushort_t* woT = base + 4 * M1;
    ushort_t* wkT = base + 8 * M1;
    ushort_t* Vt  = base + 8 * M1;
    ushort_t* wvT = base + 9 * M1;
    ushort_t* Qb  = base + 10 * M1;
    ushort_t* Kb  = base + 14 * M1;
    ushort_t* Vb  = base + 15 * M1;

    dim3 blk(256);
    const int NCONV = 2048 * 2048;

    transpose_w<<<dim3(32, 32), blk, 0, stream>>>(w_q, wqT, 2048, 2048);
    transpose_w<<<dim3(8, 32), blk, 0, stream>>>(w_k, wkT, 2048, 512);
    transpose_w<<<dim3(8, 32), blk, 0, stream>>>(w_v, wvT, 2048, 512);

    conv_bf16<<<NCONV / (256 * 8), blk, 0, stream>>>(q_embs, E, NCONV);
    gemm128<0><<<dim3(16, 16), blk, 0, stream>>>(E, wqT, Qb, 2048, 2048, 2048);

    conv_bf16<<<NCONV / (256 * 8), blk, 0, stream>>>(k_embs, E, NCONV);
    gemm64<<<dim3(8, 32), blk, 0, stream>>>(E, wkT, Kb, 2048, 512, 2048);

    conv_bf16<<<NCONV / (256 * 8), blk, 0, stream>>>(v_embs, E, NCONV);
    gemm64<<<dim3(8, 32), blk, 0, stream>>>(E, wvT, Vb, 2048, 512, 2048);

    rope_kernel<<<(2048 * 1024 + 255) / 256, blk, 0, stream>>>(Qb, 2048, 2048);
    rope_kernel<<<(2048 * 256 + 255) / 256, blk, 0, stream>>>(Kb, 2048, 512);

    // Vt aliases wkT (dead after K GEMM); woT aliases wqT (dead after Q GEMM)
    transpose_v<<<dim3(32, 8), blk, 0, stream>>>(Vb, Vt);
    transpose_w<<<dim3(32, 32), blk, 0, stream>>>(w_o, woT, 2048, 2048);

    // Ab aliases E (dead after V GEMM)
    attn_mfma<<<dim3(32, 32), blk, 0, stream>>>(Qb, Kb, Vt, Ab);

    gemm128<1><<<dim3(16, 16), blk, 0, stream>>>(Ab, woT, out, 2048, 2048, 2048);
}